// Round 1
// baseline (660.630 us; speedup 1.0000x reference)
//
#include <hip/hip_runtime.h>
#include <hip/hip_bf16.h>

#define N_NODES 100000
#define N_EDGES 1600000
#define NFEAT 128
#define PCD 32
#define KCH 4

// ---------------- workspace layout (bytes, 256-aligned) ----------------
// Wall   [128*128] f32 :       0 ..   65,536
// cbias  [128]     f32 :  65,536 ..   66,048
// p      [N*8]     f32 :  66,048 ..  3,266,048
// c      [N*128]   f32 : 3,266,048 .. 54,466,048
// ew     [E*4]     f32 : 54,466,048 .. 80,066,048
// counts [N]       i32 : 80,066,048 .. 80,466,048
// offsets[N+1]     i32 : 80,466,048 .. 80,866,052
// cursor [N]       i32 : 80,866,304 .. 81,266,304
// bsums  [128]     i32 : 81,266,304 .. 81,266,816
// csr    [E]       i32 : 81,266,816 .. 87,666,816   (~88 MB total)

#define WS_WALL    0
#define WS_CBIAS   65536
#define WS_P       66048
#define WS_C       3266048
#define WS_EW      54466048
#define WS_COUNTS  80066048
#define WS_OFFS    80466048
#define WS_CURSOR  80866304
#define WS_BSUMS   81266304
#define WS_CSR     81266816

// ---- fuse Wlin@Wconv -> Wall[f][k*32+q]; cbias = blin@Wconv ----
__global__ void k_fuse(const float* __restrict__ Wlin, const float* __restrict__ Wconv,
                       const float* __restrict__ blin, float* __restrict__ Wall,
                       float* __restrict__ cbias) {
    int tid = blockIdx.x * 256 + threadIdx.x;
    if (tid < 16384) {
        int k = tid >> 12;         // 4096 outputs per channel
        int rem = tid & 4095;
        int f = rem >> 5;
        int q = rem & 31;
        float a = 0.f;
        for (int pp = 0; pp < 32; pp++)
            a += Wlin[(k * 128 + f) * 32 + pp] * Wconv[(k * 32 + pp) * 32 + q];
        Wall[f * 128 + k * 32 + q] = a;
    } else if (tid < 16512) {
        int i = tid - 16384;
        int k = i >> 5;
        int q = i & 31;
        float a = 0.f;
        for (int pp = 0; pp < 32; pp++)
            a += blin[k * 32 + pp] * Wconv[(k * 32 + pp) * 32 + q];
        cbias[k * 32 + q] = a;
    }
}

// ---- c[N,128] = x @ Wall + cbias ; tile 64 rows/block, reg-block 8x4 ----
__global__ __launch_bounds__(256) void k_cgemm(const float* __restrict__ x,
                                               const float* __restrict__ Wall,
                                               const float* __restrict__ cbias,
                                               float* __restrict__ c) {
    __shared__ float xs[64 * 128];
    int t = threadIdx.x;
    int row0 = blockIdx.x * 64;

    // stage 64 x-rows into LDS (coalesced float4)
    const float4* xg = (const float4*)(x + (size_t)row0 * 128);
    float4* xs4 = (float4*)xs;
    for (int i = 0; i < 8; i++) {
        int idx = i * 256 + t;          // float4 index in tile, 0..2047
        int r = idx >> 5;               // row within tile
        float4 v = make_float4(0.f, 0.f, 0.f, 0.f);
        if (row0 + r < N_NODES) v = xg[idx];
        xs4[idx] = v;
    }
    __syncthreads();

    int c0 = (t & 31) * 4;              // 4 consecutive output cols
    int r0 = (t >> 5) * 8;              // 8 rows
    float acc[8][4] = {};

    for (int f4 = 0; f4 < 32; f4++) {
        float4 wf0 = *(const float4*)(Wall + (f4 * 4 + 0) * 128 + c0);
        float4 wf1 = *(const float4*)(Wall + (f4 * 4 + 1) * 128 + c0);
        float4 wf2 = *(const float4*)(Wall + (f4 * 4 + 2) * 128 + c0);
        float4 wf3 = *(const float4*)(Wall + (f4 * 4 + 3) * 128 + c0);
        for (int r = 0; r < 8; r++) {
            float4 xv = *(const float4*)(xs + (r0 + r) * 128 + f4 * 4);
            acc[r][0] += xv.x * wf0.x + xv.y * wf1.x + xv.z * wf2.x + xv.w * wf3.x;
            acc[r][1] += xv.x * wf0.y + xv.y * wf1.y + xv.z * wf2.y + xv.w * wf3.y;
            acc[r][2] += xv.x * wf0.z + xv.y * wf1.z + xv.z * wf2.z + xv.w * wf3.z;
            acc[r][3] += xv.x * wf0.w + xv.y * wf1.w + xv.z * wf2.w + xv.w * wf3.w;
        }
    }

    float4 cb = *(const float4*)(cbias + c0);
    for (int r = 0; r < 8; r++) {
        int row = row0 + r0 + r;
        if (row < N_NODES) {
            float4 o;
            o.x = acc[r][0] + cb.x;
            o.y = acc[r][1] + cb.y;
            o.z = acc[r][2] + cb.z;
            o.w = acc[r][3] + cb.w;
            *(float4*)(c + (size_t)row * 128 + c0) = o;
        }
    }
}

// ---- per-node assigner projections: p[n,0:4]=x@aW1[:128], p[n,4:8]=x@aW1[128:] ----
__global__ void k_p(const float* __restrict__ x, const float* __restrict__ aW1,
                    float* __restrict__ p) {
    int tid = blockIdx.x * 256 + threadIdx.x;
    if (tid >= N_NODES * 8) return;
    int n = tid >> 3;
    int j = tid & 7;
    int off = (j < 4) ? j : (512 + (j - 4));   // second half: aW1[(128+f)*4 + (j-4)]
    const float4* xr = (const float4*)(x + (size_t)n * 128);
    float acc = 0.f;
    for (int f4 = 0; f4 < 32; f4++) {
        float4 xv = xr[f4];
        int fb = f4 * 16;  // f*4 at f=f4*4
        acc += xv.x * aW1[fb + off];
        acc += xv.y * aW1[fb + 4 + off];
        acc += xv.z * aW1[fb + 8 + off];
        acc += xv.w * aW1[fb + 12 + off];
    }
    p[tid] = acc;
}

// ---- edge weights (softmax) + row histogram ----
__global__ void k_edge(const int* __restrict__ erow, const int* __restrict__ ecol,
                       const float* __restrict__ p, const float* __restrict__ aW2,
                       const float* __restrict__ ab1, const float* __restrict__ ab2,
                       float* __restrict__ ew, int* __restrict__ counts) {
    int e = blockIdx.x * 256 + threadIdx.x;
    if (e >= N_EDGES) return;
    int r = erow[e];
    int cl = ecol[e];
    float4 pc = *(const float4*)(p + (size_t)cl * 8);
    float4 pr = *(const float4*)(p + (size_t)r * 8 + 4);
    float h0 = pc.x + pr.x + ab1[0];
    float h1 = pc.y + pr.y + ab1[1];
    float h2 = pc.z + pr.z + ab1[2];
    float h3 = pc.w + pr.w + ab1[3];
    float s[4];
    for (int j = 0; j < 4; j++)
        s[j] = h0 * aW2[j] + h1 * aW2[4 + j] + h2 * aW2[8 + j] + h3 * aW2[12 + j] + ab2[j];
    float m = fmaxf(fmaxf(s[0], s[1]), fmaxf(s[2], s[3]));
    float e0 = expf(s[0] - m), e1 = expf(s[1] - m), e2 = expf(s[2] - m), e3 = expf(s[3] - m);
    float inv = 1.f / (e0 + e1 + e2 + e3);
    float4 w = make_float4(e0 * inv, e1 * inv, e2 * inv, e3 * inv);
    *(float4*)(ew + (size_t)e * 4) = w;
    atomicAdd(&counts[r], 1);
}

// ---- scan pass 1: per-chunk(1024) exclusive scan + chunk totals ----
__global__ __launch_bounds__(256) void k_scan1(const int* __restrict__ counts,
                                               int* __restrict__ offsets,
                                               int* __restrict__ bsums) {
    __shared__ int sd[256];
    int t = threadIdx.x;
    int b = blockIdx.x;
    int i0 = b * 1024 + t * 4;
    int v0 = (i0 + 0 < N_NODES) ? counts[i0 + 0] : 0;
    int v1 = (i0 + 1 < N_NODES) ? counts[i0 + 1] : 0;
    int v2 = (i0 + 2 < N_NODES) ? counts[i0 + 2] : 0;
    int v3 = (i0 + 3 < N_NODES) ? counts[i0 + 3] : 0;
    int ts = v0 + v1 + v2 + v3;
    sd[t] = ts;
    __syncthreads();
    for (int s = 1; s < 256; s <<= 1) {
        int add = (t >= s) ? sd[t - s] : 0;
        __syncthreads();
        sd[t] += add;
        __syncthreads();
    }
    int base = sd[t] - ts;   // exclusive prefix of this thread
    if (i0 + 0 < N_NODES) offsets[i0 + 0] = base;
    if (i0 + 1 < N_NODES) offsets[i0 + 1] = base + v0;
    if (i0 + 2 < N_NODES) offsets[i0 + 2] = base + v0 + v1;
    if (i0 + 3 < N_NODES) offsets[i0 + 3] = base + v0 + v1 + v2;
    if (t == 255) bsums[b] = sd[255];
}

// ---- scan pass 2: scan the 98 chunk totals; write grand total to offsets[N] ----
__global__ void k_scan2(int* __restrict__ bsums, int* __restrict__ offsets, int B) {
    __shared__ int sd[128];
    int t = threadIdx.x;
    int v = (t < B) ? bsums[t] : 0;
    sd[t] = v;
    __syncthreads();
    for (int s = 1; s < 128; s <<= 1) {
        int add = (t >= s) ? sd[t - s] : 0;
        __syncthreads();
        sd[t] += add;
        __syncthreads();
    }
    if (t < B) bsums[t] = sd[t] - v;      // exclusive block base
    if (t == 127) offsets[N_NODES] = sd[127];
}

// ---- scan pass 3: add chunk bases; also init cursor = offsets ----
__global__ void k_scan3(int* __restrict__ offsets, int* __restrict__ cursor,
                        const int* __restrict__ bsums) {
    int i = blockIdx.x * 256 + threadIdx.x;
    if (i < N_NODES) {
        int o = offsets[i] + bsums[i >> 10];
        offsets[i] = o;
        cursor[i] = o;
    }
}

// ---- scatter edge ids into CSR ----
__global__ void k_scatter(const int* __restrict__ erow, int* __restrict__ cursor,
                          int* __restrict__ csr) {
    int e = blockIdx.x * 256 + threadIdx.x;
    if (e >= N_EDGES) return;
    int pos = atomicAdd(&cursor[erow[e]], 1);
    csr[pos] = e;
}

// ---- aggregation (pull): wave per node; +bch, L2-norm per channel, h + logits ----
__global__ __launch_bounds__(256) void k_agg(const int* __restrict__ csr,
                                             const int* __restrict__ ecol,
                                             const float* __restrict__ ew,
                                             const float* __restrict__ c,
                                             const int* __restrict__ offsets,
                                             const float* __restrict__ bch,
                                             const float* __restrict__ Wcls,
                                             const float* __restrict__ bcls,
                                             float* __restrict__ out) {
    int wid = (blockIdx.x * 256 + threadIdx.x) >> 6;
    int lane = threadIdx.x & 63;
    if (wid >= N_NODES) return;
    int n = wid;
    int start = offsets[n];
    int end = offsets[n + 1];
    int j0 = lane;          // channel k0 = lane>>5  (0 or 1)
    int j1 = lane + 64;     // channel 2 + (lane>>5)
    int k0 = lane >> 5;

    float acc0 = 0.f, acc1 = 0.f;
    for (int idx = start; idx < end; idx++) {
        int e = csr[idx];
        int col = ecol[e];
        float w0 = ew[(size_t)e * 4 + k0];
        float w1 = ew[(size_t)e * 4 + 2 + k0];
        const float* cr = c + (size_t)col * 128;
        acc0 += w0 * cr[j0];
        acc1 += w1 * cr[j1];
    }
    float v0 = acc0 + bch[j0];
    float v1 = acc1 + bch[j1];

    float s0 = v0 * v0, s1 = v1 * v1;
    #pragma unroll
    for (int m = 1; m <= 16; m <<= 1) {
        s0 += __shfl_xor(s0, m);
        s1 += __shfl_xor(s1, m);
    }
    v0 /= fmaxf(sqrtf(s0), 1e-12f);
    v1 /= fmaxf(sqrtf(s1), 1e-12f);

    out[(size_t)n * 128 + j0] = v0;
    out[(size_t)n * 128 + j1] = v1;

    float pl = v0 * Wcls[j0] + v1 * Wcls[j1];
    #pragma unroll
    for (int m = 1; m <= 32; m <<= 1) pl += __shfl_xor(pl, m);
    if (lane == 0) out[(size_t)N_NODES * 128 + n] = pl + bcls[0];
}

extern "C" void kernel_launch(void* const* d_in, const int* in_sizes, int n_in,
                              void* d_out, int out_size, void* d_ws, size_t ws_size,
                              hipStream_t stream) {
    const float* x    = (const float*)d_in[0];
    const int*   erow = (const int*)d_in[1];
    const int*   ecol = (const int*)d_in[2];
    const float* aW1  = (const float*)d_in[3];
    const float* ab1  = (const float*)d_in[4];
    const float* aW2  = (const float*)d_in[5];
    const float* ab2  = (const float*)d_in[6];
    const float* Wlin = (const float*)d_in[7];
    const float* blin = (const float*)d_in[8];
    const float* Wconv= (const float*)d_in[9];
    const float* bch  = (const float*)d_in[10];
    const float* Wcls = (const float*)d_in[11];
    const float* bcls = (const float*)d_in[12];
    float* out = (float*)d_out;

    char* ws = (char*)d_ws;
    float* Wall   = (float*)(ws + WS_WALL);
    float* cbias  = (float*)(ws + WS_CBIAS);
    float* p      = (float*)(ws + WS_P);
    float* c      = (float*)(ws + WS_C);
    float* ew     = (float*)(ws + WS_EW);
    int*   counts = (int*)(ws + WS_COUNTS);
    int*   offs   = (int*)(ws + WS_OFFS);
    int*   cursor = (int*)(ws + WS_CURSOR);
    int*   bsums  = (int*)(ws + WS_BSUMS);
    int*   csr    = (int*)(ws + WS_CSR);

    hipMemsetAsync(counts, 0, N_NODES * sizeof(int), stream);

    k_fuse<<<65, 256, 0, stream>>>(Wlin, Wconv, blin, Wall, cbias);
    k_cgemm<<<(N_NODES + 63) / 64, 256, 0, stream>>>(x, Wall, cbias, c);
    k_p<<<(N_NODES * 8 + 255) / 256, 256, 0, stream>>>(x, aW1, p);
    k_edge<<<(N_EDGES + 255) / 256, 256, 0, stream>>>(erow, ecol, p, aW2, ab1, ab2, ew, counts);
    k_scan1<<<(N_NODES + 1023) / 1024, 256, 0, stream>>>(counts, offs, bsums);
    k_scan2<<<1, 128, 0, stream>>>(bsums, offs, (N_NODES + 1023) / 1024);
    k_scan3<<<(N_NODES + 255) / 256, 256, 0, stream>>>(offs, cursor, bsums);
    k_scatter<<<(N_EDGES + 255) / 256, 256, 0, stream>>>(erow, cursor, csr);
    k_agg<<<(N_NODES + 3) / 4, 256, 0, stream>>>(csr, ecol, ew, c, offs, bch, Wcls, bcls, out);
}

// Round 2
// 486.198 us; speedup vs baseline: 1.3588x; 1.3588x over previous
//
#include <hip/hip_runtime.h>
#include <hip/hip_bf16.h>

#define N_NODES 100000
#define N_EDGES 1600000
#define NFEAT 128
#define PCD 32
#define KCH 4

// ---------------- workspace layout (bytes) ----------------
#define WS_WALL    0           // Wall [128*128] f32, 65,536 B
#define WS_CBIAS   65536       // cbias [128] f32
#define WS_P       66048       // p [N*8] f32, 3,200,000 B
#define WS_C       3266048     // c [N*128] bf16, 25,600,000 B
#define WS_COUNTS  28866048    // counts [N] i32
#define WS_OFFS    29266048    // offsets [N+1] i32
#define WS_CURSOR  29666304    // cursor [N] i32
#define WS_BSUMS   30066304    // bsums [128] i32
#define WS_CSRCOL  30066816    // csr_col [E] i32, 6,400,000 B
#define WS_CSRW    36466816    // csr_w [E*4] f32, 25,600,000 B -> ends 62,066,816

static __device__ __forceinline__ unsigned short f2bf(float f) {
    union { float f; unsigned int u; } v; v.f = f;
    unsigned int u = v.u;
    return (unsigned short)((u + 0x7fffu + ((u >> 16) & 1u)) >> 16);  // RNE
}

// ---- fuse Wlin@Wconv -> Wall[f][k*32+q]; cbias = blin@Wconv ----
__global__ void k_fuse(const float* __restrict__ Wlin, const float* __restrict__ Wconv,
                       const float* __restrict__ blin, float* __restrict__ Wall,
                       float* __restrict__ cbias) {
    int tid = blockIdx.x * 256 + threadIdx.x;
    if (tid < 16384) {
        int k = tid >> 12;
        int rem = tid & 4095;
        int f = rem >> 5;
        int q = rem & 31;
        float a = 0.f;
        for (int pp = 0; pp < 32; pp++)
            a += Wlin[(k * 128 + f) * 32 + pp] * Wconv[(k * 32 + pp) * 32 + q];
        Wall[f * 128 + k * 32 + q] = a;
    } else if (tid < 16512) {
        int i = tid - 16384;
        int k = i >> 5;
        int q = i & 31;
        float a = 0.f;
        for (int pp = 0; pp < 32; pp++)
            a += blin[k * 32 + pp] * Wconv[(k * 32 + pp) * 32 + q];
        cbias[k * 32 + q] = a;
    }
}

// ---- c[N,128] = bf16(x @ Wall + cbias) ; tile 64 rows/block, reg-block 8x4 ----
__global__ __launch_bounds__(256) void k_cgemm(const float* __restrict__ x,
                                               const float* __restrict__ Wall,
                                               const float* __restrict__ cbias,
                                               unsigned short* __restrict__ c) {
    __shared__ float xs[64 * 128];
    int t = threadIdx.x;
    int row0 = blockIdx.x * 64;

    const float4* xg = (const float4*)(x + (size_t)row0 * 128);
    float4* xs4 = (float4*)xs;
    for (int i = 0; i < 8; i++) {
        int idx = i * 256 + t;
        int r = idx >> 5;
        float4 v = make_float4(0.f, 0.f, 0.f, 0.f);
        if (row0 + r < N_NODES) v = xg[idx];
        xs4[idx] = v;
    }
    __syncthreads();

    int c0 = (t & 31) * 4;
    int r0 = (t >> 5) * 8;
    float acc[8][4] = {};

    for (int f4 = 0; f4 < 32; f4++) {
        float4 wf0 = *(const float4*)(Wall + (f4 * 4 + 0) * 128 + c0);
        float4 wf1 = *(const float4*)(Wall + (f4 * 4 + 1) * 128 + c0);
        float4 wf2 = *(const float4*)(Wall + (f4 * 4 + 2) * 128 + c0);
        float4 wf3 = *(const float4*)(Wall + (f4 * 4 + 3) * 128 + c0);
        for (int r = 0; r < 8; r++) {
            float4 xv = *(const float4*)(xs + (r0 + r) * 128 + f4 * 4);
            acc[r][0] += xv.x * wf0.x + xv.y * wf1.x + xv.z * wf2.x + xv.w * wf3.x;
            acc[r][1] += xv.x * wf0.y + xv.y * wf1.y + xv.z * wf2.y + xv.w * wf3.y;
            acc[r][2] += xv.x * wf0.z + xv.y * wf1.z + xv.z * wf2.z + xv.w * wf3.z;
            acc[r][3] += xv.x * wf0.w + xv.y * wf1.w + xv.z * wf2.w + xv.w * wf3.w;
        }
    }

    float4 cb = *(const float4*)(cbias + c0);
    for (int r = 0; r < 8; r++) {
        int row = row0 + r0 + r;
        if (row < N_NODES) {
            ushort4 o;
            o.x = f2bf(acc[r][0] + cb.x);
            o.y = f2bf(acc[r][1] + cb.y);
            o.z = f2bf(acc[r][2] + cb.z);
            o.w = f2bf(acc[r][3] + cb.w);
            *(ushort4*)(c + (size_t)row * 128 + c0) = o;
        }
    }
}

// ---- per-node assigner projections ----
__global__ void k_p(const float* __restrict__ x, const float* __restrict__ aW1,
                    float* __restrict__ p) {
    int tid = blockIdx.x * 256 + threadIdx.x;
    if (tid >= N_NODES * 8) return;
    int n = tid >> 3;
    int j = tid & 7;
    int off = (j < 4) ? j : (512 + (j - 4));
    const float4* xr = (const float4*)(x + (size_t)n * 128);
    float acc = 0.f;
    for (int f4 = 0; f4 < 32; f4++) {
        float4 xv = xr[f4];
        int fb = f4 * 16;
        acc += xv.x * aW1[fb + off];
        acc += xv.y * aW1[fb + 4 + off];
        acc += xv.z * aW1[fb + 8 + off];
        acc += xv.w * aW1[fb + 12 + off];
    }
    p[tid] = acc;
}

// ---- row histogram ----
__global__ void k_count(const int* __restrict__ erow, int* __restrict__ counts) {
    int e = blockIdx.x * 256 + threadIdx.x;
    if (e < N_EDGES) atomicAdd(&counts[erow[e]], 1);
}

// ---- scan pass 1 ----
__global__ __launch_bounds__(256) void k_scan1(const int* __restrict__ counts,
                                               int* __restrict__ offsets,
                                               int* __restrict__ bsums) {
    __shared__ int sd[256];
    int t = threadIdx.x;
    int b = blockIdx.x;
    int i0 = b * 1024 + t * 4;
    int v0 = (i0 + 0 < N_NODES) ? counts[i0 + 0] : 0;
    int v1 = (i0 + 1 < N_NODES) ? counts[i0 + 1] : 0;
    int v2 = (i0 + 2 < N_NODES) ? counts[i0 + 2] : 0;
    int v3 = (i0 + 3 < N_NODES) ? counts[i0 + 3] : 0;
    int ts = v0 + v1 + v2 + v3;
    sd[t] = ts;
    __syncthreads();
    for (int s = 1; s < 256; s <<= 1) {
        int add = (t >= s) ? sd[t - s] : 0;
        __syncthreads();
        sd[t] += add;
        __syncthreads();
    }
    int base = sd[t] - ts;
    if (i0 + 0 < N_NODES) offsets[i0 + 0] = base;
    if (i0 + 1 < N_NODES) offsets[i0 + 1] = base + v0;
    if (i0 + 2 < N_NODES) offsets[i0 + 2] = base + v0 + v1;
    if (i0 + 3 < N_NODES) offsets[i0 + 3] = base + v0 + v1 + v2;
    if (t == 255) bsums[b] = sd[255];
}

// ---- scan pass 2 ----
__global__ void k_scan2(int* __restrict__ bsums, int* __restrict__ offsets, int B) {
    __shared__ int sd[128];
    int t = threadIdx.x;
    int v = (t < B) ? bsums[t] : 0;
    sd[t] = v;
    __syncthreads();
    for (int s = 1; s < 128; s <<= 1) {
        int add = (t >= s) ? sd[t - s] : 0;
        __syncthreads();
        sd[t] += add;
        __syncthreads();
    }
    if (t < B) bsums[t] = sd[t] - v;
    if (t == 127) offsets[N_NODES] = sd[127];
}

// ---- scan pass 3: finalize offsets, init cursor ----
__global__ void k_scan3(int* __restrict__ offsets, int* __restrict__ cursor,
                        const int* __restrict__ bsums) {
    int i = blockIdx.x * 256 + threadIdx.x;
    if (i < N_NODES) {
        int o = offsets[i] + bsums[i >> 10];
        offsets[i] = o;
        cursor[i] = o;
    }
}

// ---- edge softmax + direct CSR scatter of (col, w4) ----
__global__ void k_edge_scatter(const int* __restrict__ erow, const int* __restrict__ ecol,
                               const float* __restrict__ p, const float* __restrict__ aW2,
                               const float* __restrict__ ab1, const float* __restrict__ ab2,
                               int* __restrict__ cursor, int* __restrict__ csr_col,
                               float* __restrict__ csr_w) {
    int e = blockIdx.x * 256 + threadIdx.x;
    if (e >= N_EDGES) return;
    int r = erow[e];
    int cl = ecol[e];
    float4 pc = *(const float4*)(p + (size_t)cl * 8);
    float4 pr = *(const float4*)(p + (size_t)r * 8 + 4);
    float h0 = pc.x + pr.x + ab1[0];
    float h1 = pc.y + pr.y + ab1[1];
    float h2 = pc.z + pr.z + ab1[2];
    float h3 = pc.w + pr.w + ab1[3];
    float s[4];
    for (int j = 0; j < 4; j++)
        s[j] = h0 * aW2[j] + h1 * aW2[4 + j] + h2 * aW2[8 + j] + h3 * aW2[12 + j] + ab2[j];
    float m = fmaxf(fmaxf(s[0], s[1]), fmaxf(s[2], s[3]));
    float e0 = expf(s[0] - m), e1 = expf(s[1] - m), e2 = expf(s[2] - m), e3 = expf(s[3] - m);
    float inv = 1.f / (e0 + e1 + e2 + e3);
    float4 w = make_float4(e0 * inv, e1 * inv, e2 * inv, e3 * inv);
    int pos = atomicAdd(&cursor[r], 1);
    csr_col[pos] = cl;
    *(float4*)(csr_w + (size_t)pos * 4) = w;
}

// ---- aggregation (pull): wave per node; bf16 c gather; norm + classifier fused ----
__global__ __launch_bounds__(256) void k_agg(const int* __restrict__ csr_col,
                                             const float* __restrict__ csr_w,
                                             const unsigned int* __restrict__ c4,
                                             const int* __restrict__ offsets,
                                             const float* __restrict__ bch,
                                             const float* __restrict__ Wcls,
                                             const float* __restrict__ bcls,
                                             float* __restrict__ out) {
    int wid = (blockIdx.x * 256 + threadIdx.x) >> 6;
    int lane = threadIdx.x & 63;
    if (wid >= N_NODES) return;
    int n = wid;
    int start = offsets[n];
    int end = offsets[n + 1];
    int ch = lane >> 4;               // channel of features 2*lane, 2*lane+1

    float acc0 = 0.f, acc1 = 0.f;     // features f0=2*lane, f1=2*lane+1
    int idx = start;
    for (; idx + 1 < end; idx += 2) {
        int col0 = csr_col[idx];
        int col1 = csr_col[idx + 1];
        float w0 = csr_w[(size_t)idx * 4 + ch];
        float w1 = csr_w[(size_t)(idx + 1) * 4 + ch];
        unsigned int u0 = c4[(size_t)col0 * 64 + lane];
        unsigned int u1 = c4[(size_t)col1 * 64 + lane];
        float lo0 = __uint_as_float(u0 << 16);
        float hi0 = __uint_as_float(u0 & 0xffff0000u);
        float lo1 = __uint_as_float(u1 << 16);
        float hi1 = __uint_as_float(u1 & 0xffff0000u);
        acc0 += w0 * lo0 + w1 * lo1;
        acc1 += w0 * hi0 + w1 * hi1;
    }
    if (idx < end) {
        int col0 = csr_col[idx];
        float w0 = csr_w[(size_t)idx * 4 + ch];
        unsigned int u0 = c4[(size_t)col0 * 64 + lane];
        acc0 += w0 * __uint_as_float(u0 << 16);
        acc1 += w0 * __uint_as_float(u0 & 0xffff0000u);
    }

    int f0 = 2 * lane, f1 = 2 * lane + 1;
    float v0 = acc0 + bch[f0];
    float v1 = acc1 + bch[f1];

    float ss = v0 * v0 + v1 * v1;     // reduce over the 16 lanes of this channel
    #pragma unroll
    for (int m = 1; m <= 8; m <<= 1) ss += __shfl_xor(ss, m);
    float inv = 1.f / fmaxf(sqrtf(ss), 1e-12f);
    v0 *= inv;
    v1 *= inv;

    *(float2*)(out + (size_t)n * 128 + f0) = make_float2(v0, v1);

    float pl = v0 * Wcls[f0] + v1 * Wcls[f1];
    #pragma unroll
    for (int m = 1; m <= 32; m <<= 1) pl += __shfl_xor(pl, m);
    if (lane == 0) out[(size_t)N_NODES * 128 + n] = pl + bcls[0];
}

extern "C" void kernel_launch(void* const* d_in, const int* in_sizes, int n_in,
                              void* d_out, int out_size, void* d_ws, size_t ws_size,
                              hipStream_t stream) {
    const float* x    = (const float*)d_in[0];
    const int*   erow = (const int*)d_in[1];
    const int*   ecol = (const int*)d_in[2];
    const float* aW1  = (const float*)d_in[3];
    const float* ab1  = (const float*)d_in[4];
    const float* aW2  = (const float*)d_in[5];
    const float* ab2  = (const float*)d_in[6];
    const float* Wlin = (const float*)d_in[7];
    const float* blin = (const float*)d_in[8];
    const float* Wconv= (const float*)d_in[9];
    const float* bch  = (const float*)d_in[10];
    const float* Wcls = (const float*)d_in[11];
    const float* bcls = (const float*)d_in[12];
    float* out = (float*)d_out;

    char* ws = (char*)d_ws;
    float*          Wall    = (float*)(ws + WS_WALL);
    float*          cbias   = (float*)(ws + WS_CBIAS);
    float*          p       = (float*)(ws + WS_P);
    unsigned short* c       = (unsigned short*)(ws + WS_C);
    int*            counts  = (int*)(ws + WS_COUNTS);
    int*            offs    = (int*)(ws + WS_OFFS);
    int*            cursor  = (int*)(ws + WS_CURSOR);
    int*            bsums   = (int*)(ws + WS_BSUMS);
    int*            csr_col = (int*)(ws + WS_CSRCOL);
    float*          csr_w   = (float*)(ws + WS_CSRW);

    hipMemsetAsync(counts, 0, N_NODES * sizeof(int), stream);

    k_fuse<<<65, 256, 0, stream>>>(Wlin, Wconv, blin, Wall, cbias);
    k_cgemm<<<(N_NODES + 63) / 64, 256, 0, stream>>>(x, Wall, cbias, c);
    k_p<<<(N_NODES * 8 + 255) / 256, 256, 0, stream>>>(x, aW1, p);
    k_count<<<(N_EDGES + 255) / 256, 256, 0, stream>>>(erow, counts);
    k_scan1<<<(N_NODES + 1023) / 1024, 256, 0, stream>>>(counts, offs, bsums);
    k_scan2<<<1, 128, 0, stream>>>(bsums, offs, (N_NODES + 1023) / 1024);
    k_scan3<<<(N_NODES + 255) / 256, 256, 0, stream>>>(offs, cursor, bsums);
    k_edge_scatter<<<(N_EDGES + 255) / 256, 256, 0, stream>>>(erow, ecol, p, aW2, ab1, ab2,
                                                              cursor, csr_col, csr_w);
    k_agg<<<(N_NODES + 3) / 4, 256, 0, stream>>>(csr_col, csr_w, (const unsigned int*)c,
                                                 offs, bch, Wcls, bcls, out);
}

// Round 3
// 424.125 us; speedup vs baseline: 1.5576x; 1.1464x over previous
//
#include <hip/hip_runtime.h>
#include <hip/hip_bf16.h>

#define N_NODES 100000
#define N_EDGES 1600000
#define NFEAT 128
#define PCD 32
#define KCH 4

// ---------------- workspace layout (bytes) ----------------
#define WS_WALL    0           // Wall [128*128] f32, 65,536 B
#define WS_CBIAS   65536       // cbias [128] f32
#define WS_P       66048       // p [N*8] f32, 3,200,000 B
#define WS_C       3266048     // c [N*128] bf16, 25,600,000 B -> 28,866,048
#define WS_COUNTS  28866048    // counts [N] i32 -> 29,266,048
#define WS_OFFS    29266048    // offsets [N+1] i32 -> 29,666,052
#define WS_CURSOR  29666304    // cursor [N] i32 -> 30,066,304
#define WS_BSUMS   30066304    // bsums [128] i32 -> 30,066,816
#define WS_CSRCOL  30066816    // csr_col [E] i32 -> 36,466,816
#define WS_CSRW    36466816    // csr_w [E*2] u32 (4x bf16) -> 49,266,816

static __device__ __forceinline__ unsigned short f2bf(float f) {
    union { float f; unsigned int u; } v; v.f = f;
    unsigned int u = v.u;
    return (unsigned short)((u + 0x7fffu + ((u >> 16) & 1u)) >> 16);  // RNE
}

// ---- fuse Wlin@Wconv -> Wall[f][k*32+q]; cbias = blin@Wconv ----
__global__ void k_fuse(const float* __restrict__ Wlin, const float* __restrict__ Wconv,
                       const float* __restrict__ blin, float* __restrict__ Wall,
                       float* __restrict__ cbias) {
    int tid = blockIdx.x * 256 + threadIdx.x;
    if (tid < 16384) {
        int k = tid >> 12;
        int rem = tid & 4095;
        int f = rem >> 5;
        int q = rem & 31;
        float a = 0.f;
        for (int pp = 0; pp < 32; pp++)
            a += Wlin[(k * 128 + f) * 32 + pp] * Wconv[(k * 32 + pp) * 32 + q];
        Wall[f * 128 + k * 32 + q] = a;
    } else if (tid < 16512) {
        int i = tid - 16384;
        int k = i >> 5;
        int q = i & 31;
        float a = 0.f;
        for (int pp = 0; pp < 32; pp++)
            a += blin[k * 32 + pp] * Wconv[(k * 32 + pp) * 32 + q];
        cbias[k * 32 + q] = a;
    }
}

// ---- c[N,128] = bf16(x @ Wall + cbias)  AND  p[N,8] = x @ [aW1_lo | aW1_hi] ----
// x tile (64 rows) staged once in LDS, used for both outputs.
#define XS_LD 132   // padded leading dim (floats)
__global__ __launch_bounds__(256) void k_cgemm(const float* __restrict__ x,
                                               const float* __restrict__ Wall,
                                               const float* __restrict__ cbias,
                                               const float* __restrict__ aW1,
                                               unsigned short* __restrict__ c,
                                               float* __restrict__ p) {
    __shared__ float xs[64 * XS_LD];       // 33,792 B
    __shared__ float aT[8 * XS_LD];        // 4,224 B  (aT[j][f] = proj col j)
    int t = threadIdx.x;
    int row0 = blockIdx.x * 64;

    // stage aW1 transposed: j<4 -> aW1[f*4+j]; j>=4 -> aW1[512 + f*4 + (j-4)]
    for (int i = t; i < 1024; i += 256) {
        int j = i >> 7;
        int f = i & 127;
        float v = (j < 4) ? aW1[f * 4 + j] : aW1[512 + f * 4 + (j - 4)];
        aT[j * XS_LD + f] = v;
    }

    // stage 64 x-rows into LDS (coalesced float4, padded stride)
    const float4* xg = (const float4*)(x + (size_t)row0 * 128);
    for (int i = 0; i < 8; i++) {
        int idx = i * 256 + t;             // float4 index in tile, 0..2047
        int r = idx >> 5;
        int cc = idx & 31;
        float4 v = make_float4(0.f, 0.f, 0.f, 0.f);
        if (row0 + r < N_NODES) v = xg[idx];
        *(float4*)(xs + r * XS_LD + cc * 4) = v;
    }
    __syncthreads();

    int c0 = (t & 31) * 4;
    int r0 = (t >> 5) * 8;
    float acc[8][4] = {};

    for (int f4 = 0; f4 < 32; f4++) {
        float4 wf0 = *(const float4*)(Wall + (f4 * 4 + 0) * 128 + c0);
        float4 wf1 = *(const float4*)(Wall + (f4 * 4 + 1) * 128 + c0);
        float4 wf2 = *(const float4*)(Wall + (f4 * 4 + 2) * 128 + c0);
        float4 wf3 = *(const float4*)(Wall + (f4 * 4 + 3) * 128 + c0);
        for (int r = 0; r < 8; r++) {
            float4 xv = *(const float4*)(xs + (r0 + r) * XS_LD + f4 * 4);
            acc[r][0] += xv.x * wf0.x + xv.y * wf1.x + xv.z * wf2.x + xv.w * wf3.x;
            acc[r][1] += xv.x * wf0.y + xv.y * wf1.y + xv.z * wf2.y + xv.w * wf3.y;
            acc[r][2] += xv.x * wf0.z + xv.y * wf1.z + xv.z * wf2.z + xv.w * wf3.z;
            acc[r][3] += xv.x * wf0.w + xv.y * wf1.w + xv.z * wf2.w + xv.w * wf3.w;
        }
    }

    float4 cb = *(const float4*)(cbias + c0);
    for (int r = 0; r < 8; r++) {
        int row = row0 + r0 + r;
        if (row < N_NODES) {
            ushort4 o;
            o.x = f2bf(acc[r][0] + cb.x);
            o.y = f2bf(acc[r][1] + cb.y);
            o.z = f2bf(acc[r][2] + cb.z);
            o.w = f2bf(acc[r][3] + cb.w);
            *(ushort4*)(c + (size_t)row * 128 + c0) = o;
        }
    }

    // epilogue: p[row][j] for the same 64 rows (x still in LDS)
    int j = t & 7;
    const float* arow = aT + j * XS_LD;
    for (int pass = 0; pass < 2; pass++) {
        int r = (t >> 3) + pass * 32;
        const float* xrow = xs + r * XS_LD;
        float accp = 0.f;
        for (int f4 = 0; f4 < 32; f4++) {
            float4 xv = *(const float4*)(xrow + f4 * 4);
            float4 av = *(const float4*)(arow + f4 * 4);
            accp += xv.x * av.x + xv.y * av.y + xv.z * av.z + xv.w * av.w;
        }
        int row = row0 + r;
        if (row < N_NODES) p[(size_t)row * 8 + j] = accp;
    }
}

// ---- row histogram ----
__global__ void k_count(const int* __restrict__ erow, int* __restrict__ counts) {
    int e = blockIdx.x * 256 + threadIdx.x;
    if (e < N_EDGES) atomicAdd(&counts[erow[e]], 1);
}

// ---- scan pass 1 ----
__global__ __launch_bounds__(256) void k_scan1(const int* __restrict__ counts,
                                               int* __restrict__ offsets,
                                               int* __restrict__ bsums) {
    __shared__ int sd[256];
    int t = threadIdx.x;
    int b = blockIdx.x;
    int i0 = b * 1024 + t * 4;
    int v0 = (i0 + 0 < N_NODES) ? counts[i0 + 0] : 0;
    int v1 = (i0 + 1 < N_NODES) ? counts[i0 + 1] : 0;
    int v2 = (i0 + 2 < N_NODES) ? counts[i0 + 2] : 0;
    int v3 = (i0 + 3 < N_NODES) ? counts[i0 + 3] : 0;
    int ts = v0 + v1 + v2 + v3;
    sd[t] = ts;
    __syncthreads();
    for (int s = 1; s < 256; s <<= 1) {
        int add = (t >= s) ? sd[t - s] : 0;
        __syncthreads();
        sd[t] += add;
        __syncthreads();
    }
    int base = sd[t] - ts;
    if (i0 + 0 < N_NODES) offsets[i0 + 0] = base;
    if (i0 + 1 < N_NODES) offsets[i0 + 1] = base + v0;
    if (i0 + 2 < N_NODES) offsets[i0 + 2] = base + v0 + v1;
    if (i0 + 3 < N_NODES) offsets[i0 + 3] = base + v0 + v1 + v2;
    if (t == 255) bsums[b] = sd[255];
}

// ---- scan pass 2 ----
__global__ void k_scan2(int* __restrict__ bsums, int* __restrict__ offsets, int B) {
    __shared__ int sd[128];
    int t = threadIdx.x;
    int v = (t < B) ? bsums[t] : 0;
    sd[t] = v;
    __syncthreads();
    for (int s = 1; s < 128; s <<= 1) {
        int add = (t >= s) ? sd[t - s] : 0;
        __syncthreads();
        sd[t] += add;
        __syncthreads();
    }
    if (t < B) bsums[t] = sd[t] - v;
    if (t == 127) offsets[N_NODES] = sd[127];
}

// ---- scan pass 3: finalize offsets, init cursor ----
__global__ void k_scan3(int* __restrict__ offsets, int* __restrict__ cursor,
                        const int* __restrict__ bsums) {
    int i = blockIdx.x * 256 + threadIdx.x;
    if (i < N_NODES) {
        int o = offsets[i] + bsums[i >> 10];
        offsets[i] = o;
        cursor[i] = o;
    }
}

// ---- edge softmax + direct CSR scatter of (col, w as 4x bf16) ----
__global__ void k_edge_scatter(const int* __restrict__ erow, const int* __restrict__ ecol,
                               const float* __restrict__ p, const float* __restrict__ aW2,
                               const float* __restrict__ ab1, const float* __restrict__ ab2,
                               int* __restrict__ cursor, int* __restrict__ csr_col,
                               unsigned int* __restrict__ csr_w) {
    int e = blockIdx.x * 256 + threadIdx.x;
    if (e >= N_EDGES) return;
    int r = erow[e];
    int cl = ecol[e];
    float4 pc = *(const float4*)(p + (size_t)cl * 8);
    float4 pr = *(const float4*)(p + (size_t)r * 8 + 4);
    float h0 = pc.x + pr.x + ab1[0];
    float h1 = pc.y + pr.y + ab1[1];
    float h2 = pc.z + pr.z + ab1[2];
    float h3 = pc.w + pr.w + ab1[3];
    float s[4];
    for (int j = 0; j < 4; j++)
        s[j] = h0 * aW2[j] + h1 * aW2[4 + j] + h2 * aW2[8 + j] + h3 * aW2[12 + j] + ab2[j];
    float m = fmaxf(fmaxf(s[0], s[1]), fmaxf(s[2], s[3]));
    float e0 = expf(s[0] - m), e1 = expf(s[1] - m), e2 = expf(s[2] - m), e3 = expf(s[3] - m);
    float inv = 1.f / (e0 + e1 + e2 + e3);
    unsigned int w01 = (unsigned int)f2bf(e0 * inv) | ((unsigned int)f2bf(e1 * inv) << 16);
    unsigned int w23 = (unsigned int)f2bf(e2 * inv) | ((unsigned int)f2bf(e3 * inv) << 16);
    int pos = atomicAdd(&cursor[r], 1);
    csr_col[pos] = cl;
    uint2 wp; wp.x = w01; wp.y = w23;
    *(uint2*)(csr_w + (size_t)pos * 2) = wp;
}

// ---- aggregation (pull): wave per node; bf16 c + bf16 w; norm + classifier fused ----
static __device__ __forceinline__ float bf_lo(unsigned int u) { return __uint_as_float(u << 16); }
static __device__ __forceinline__ float bf_hi(unsigned int u) { return __uint_as_float(u & 0xffff0000u); }

__global__ __launch_bounds__(256) void k_agg(const int* __restrict__ csr_col,
                                             const unsigned int* __restrict__ csr_w,
                                             const unsigned int* __restrict__ c4,
                                             const int* __restrict__ offsets,
                                             const float* __restrict__ bch,
                                             const float* __restrict__ Wcls,
                                             const float* __restrict__ bcls,
                                             float* __restrict__ out) {
    int wid = (blockIdx.x * 256 + threadIdx.x) >> 6;
    int lane = threadIdx.x & 63;
    if (wid >= N_NODES) return;
    int n = wid;
    int start = offsets[n];
    int end = offsets[n + 1];
    int ch = lane >> 4;               // channel of features 2*lane, 2*lane+1
    int pair = ch >> 1;               // which packed uint holds this channel's w
    int hi = ch & 1;

    float acc0 = 0.f, acc1 = 0.f;     // features f0=2*lane, f1=2*lane+1
    int idx = start;
    for (; idx + 3 < end; idx += 4) {
        int col0 = csr_col[idx];
        int col1 = csr_col[idx + 1];
        int col2 = csr_col[idx + 2];
        int col3 = csr_col[idx + 3];
        unsigned int wu0 = csr_w[(size_t)(idx + 0) * 2 + pair];
        unsigned int wu1 = csr_w[(size_t)(idx + 1) * 2 + pair];
        unsigned int wu2 = csr_w[(size_t)(idx + 2) * 2 + pair];
        unsigned int wu3 = csr_w[(size_t)(idx + 3) * 2 + pair];
        unsigned int u0 = c4[(size_t)col0 * 64 + lane];
        unsigned int u1 = c4[(size_t)col1 * 64 + lane];
        unsigned int u2 = c4[(size_t)col2 * 64 + lane];
        unsigned int u3 = c4[(size_t)col3 * 64 + lane];
        float w0 = hi ? bf_hi(wu0) : bf_lo(wu0);
        float w1 = hi ? bf_hi(wu1) : bf_lo(wu1);
        float w2 = hi ? bf_hi(wu2) : bf_lo(wu2);
        float w3 = hi ? bf_hi(wu3) : bf_lo(wu3);
        acc0 += w0 * bf_lo(u0) + w1 * bf_lo(u1) + w2 * bf_lo(u2) + w3 * bf_lo(u3);
        acc1 += w0 * bf_hi(u0) + w1 * bf_hi(u1) + w2 * bf_hi(u2) + w3 * bf_hi(u3);
    }
    for (; idx < end; idx++) {
        int col0 = csr_col[idx];
        unsigned int wu0 = csr_w[(size_t)idx * 2 + pair];
        unsigned int u0 = c4[(size_t)col0 * 64 + lane];
        float w0 = hi ? bf_hi(wu0) : bf_lo(wu0);
        acc0 += w0 * bf_lo(u0);
        acc1 += w0 * bf_hi(u0);
    }

    int f0 = 2 * lane, f1 = 2 * lane + 1;
    float v0 = acc0 + bch[f0];
    float v1 = acc1 + bch[f1];

    float ss = v0 * v0 + v1 * v1;     // reduce over the 16 lanes of this channel
    #pragma unroll
    for (int m = 1; m <= 8; m <<= 1) ss += __shfl_xor(ss, m);
    float inv = 1.f / fmaxf(sqrtf(ss), 1e-12f);
    v0 *= inv;
    v1 *= inv;

    *(float2*)(out + (size_t)n * 128 + f0) = make_float2(v0, v1);

    float pl = v0 * Wcls[f0] + v1 * Wcls[f1];
    #pragma unroll
    for (int m = 1; m <= 32; m <<= 1) pl += __shfl_xor(pl, m);
    if (lane == 0) out[(size_t)N_NODES * 128 + n] = pl + bcls[0];
}

extern "C" void kernel_launch(void* const* d_in, const int* in_sizes, int n_in,
                              void* d_out, int out_size, void* d_ws, size_t ws_size,
                              hipStream_t stream) {
    const float* x    = (const float*)d_in[0];
    const int*   erow = (const int*)d_in[1];
    const int*   ecol = (const int*)d_in[2];
    const float* aW1  = (const float*)d_in[3];
    const float* ab1  = (const float*)d_in[4];
    const float* aW2  = (const float*)d_in[5];
    const float* ab2  = (const float*)d_in[6];
    const float* Wlin = (const float*)d_in[7];
    const float* blin = (const float*)d_in[8];
    const float* Wconv= (const float*)d_in[9];
    const float* bch  = (const float*)d_in[10];
    const float* Wcls = (const float*)d_in[11];
    const float* bcls = (const float*)d_in[12];
    float* out = (float*)d_out;

    char* ws = (char*)d_ws;
    float*          Wall    = (float*)(ws + WS_WALL);
    float*          cbias   = (float*)(ws + WS_CBIAS);
    float*          p       = (float*)(ws + WS_P);
    unsigned short* c       = (unsigned short*)(ws + WS_C);
    int*            counts  = (int*)(ws + WS_COUNTS);
    int*            offs    = (int*)(ws + WS_OFFS);
    int*            cursor  = (int*)(ws + WS_CURSOR);
    int*            bsums   = (int*)(ws + WS_BSUMS);
    int*            csr_col = (int*)(ws + WS_CSRCOL);
    unsigned int*   csr_w   = (unsigned int*)(ws + WS_CSRW);

    hipMemsetAsync(counts, 0, N_NODES * sizeof(int), stream);

    k_fuse<<<65, 256, 0, stream>>>(Wlin, Wconv, blin, Wall, cbias);
    k_count<<<(N_EDGES + 255) / 256, 256, 0, stream>>>(erow, counts);
    k_cgemm<<<(N_NODES + 63) / 64, 256, 0, stream>>>(x, Wall, cbias, aW1, c, p);
    k_scan1<<<(N_NODES + 1023) / 1024, 256, 0, stream>>>(counts, offs, bsums);
    k_scan2<<<1, 128, 0, stream>>>(bsums, offs, (N_NODES + 1023) / 1024);
    k_scan3<<<(N_NODES + 255) / 256, 256, 0, stream>>>(offs, cursor, bsums);
    k_edge_scatter<<<(N_EDGES + 255) / 256, 256, 0, stream>>>(erow, ecol, p, aW2, ab1, ab2,
                                                              cursor, csr_col, csr_w);
    k_agg<<<(N_NODES + 3) / 4, 256, 0, stream>>>(csr_col, csr_w, (const unsigned int*)c,
                                                 offs, bch, Wcls, bcls, out);
}

// Round 4
// 331.444 us; speedup vs baseline: 1.9932x; 1.2796x over previous
//
#include <hip/hip_runtime.h>
#include <hip/hip_bf16.h>

#define N_NODES 100000
#define N_EDGES 1600000
#define NFEAT 128
#define PCD 32
#define KCH 4

#define TILE_E 4096
#define T_TILES 391            // ceil(N_EDGES / TILE_E)
#define BSH 8
#define NB 391                 // ceil(N_NODES / 256)
#define NHIST (NB * T_TILES)   // 152,881

// ---------------- workspace layout (bytes) ----------------
#define WS_WALL    0           // Wall [128*128] f32 -> 65,536
#define WS_CBIAS   65536       // cbias [128] f32 -> 66,048
#define WS_P       66048       // p [N*8] f32 -> 3,266,048
#define WS_C       3266048     // c [N*128] bf16 -> 28,866,048
#define WS_OFFS    28866048    // offs [N+1] i32 -> 29,266,052
#define WS_HIST    29266176    // hist [NB*T] i32 -> 29,877,700
#define WS_HSUMS   29877760    // hsums [256] i32 -> 29,878,784
#define WS_BUCK    29878784    // bucketed [E] uint2 -> 42,678,784
#define WS_CSRCOL  42678784    // csr_col [E] i32 -> 49,078,784
#define WS_CSRW    49078784    // csr_w [E*2] u32 -> 61,878,784

static __device__ __forceinline__ unsigned short f2bf(float f) {
    union { float f; unsigned int u; } v; v.f = f;
    unsigned int u = v.u;
    return (unsigned short)((u + 0x7fffu + ((u >> 16) & 1u)) >> 16);  // RNE
}

// ---- fuse Wlin@Wconv -> Wall[f][k*32+q]; cbias = blin@Wconv ----
__global__ void k_fuse(const float* __restrict__ Wlin, const float* __restrict__ Wconv,
                       const float* __restrict__ blin, float* __restrict__ Wall,
                       float* __restrict__ cbias) {
    int tid = blockIdx.x * 256 + threadIdx.x;
    if (tid < 16384) {
        int k = tid >> 12;
        int rem = tid & 4095;
        int f = rem >> 5;
        int q = rem & 31;
        float a = 0.f;
        for (int pp = 0; pp < 32; pp++)
            a += Wlin[(k * 128 + f) * 32 + pp] * Wconv[(k * 32 + pp) * 32 + q];
        Wall[f * 128 + k * 32 + q] = a;
    } else if (tid < 16512) {
        int i = tid - 16384;
        int k = i >> 5;
        int q = i & 31;
        float a = 0.f;
        for (int pp = 0; pp < 32; pp++)
            a += blin[k * 32 + pp] * Wconv[(k * 32 + pp) * 32 + q];
        cbias[k * 32 + q] = a;
    }
}

// ---- c[N,128] = bf16(x @ Wall + cbias)  AND  p[N,8] = x @ [aW1_lo | aW1_hi] ----
#define XS_LD 132
__global__ __launch_bounds__(256) void k_cgemm(const float* __restrict__ x,
                                               const float* __restrict__ Wall,
                                               const float* __restrict__ cbias,
                                               const float* __restrict__ aW1,
                                               unsigned short* __restrict__ c,
                                               float* __restrict__ p) {
    __shared__ float xs[64 * XS_LD];
    __shared__ float aT[8 * XS_LD];
    int t = threadIdx.x;
    int row0 = blockIdx.x * 64;

    for (int i = t; i < 1024; i += 256) {
        int j = i >> 7;
        int f = i & 127;
        float v = (j < 4) ? aW1[f * 4 + j] : aW1[512 + f * 4 + (j - 4)];
        aT[j * XS_LD + f] = v;
    }

    const float4* xg = (const float4*)(x + (size_t)row0 * 128);
    for (int i = 0; i < 8; i++) {
        int idx = i * 256 + t;
        int r = idx >> 5;
        int cc = idx & 31;
        float4 v = make_float4(0.f, 0.f, 0.f, 0.f);
        if (row0 + r < N_NODES) v = xg[idx];
        *(float4*)(xs + r * XS_LD + cc * 4) = v;
    }
    __syncthreads();

    int c0 = (t & 31) * 4;
    int r0 = (t >> 5) * 8;
    float acc[8][4] = {};

    for (int f4 = 0; f4 < 32; f4++) {
        float4 wf0 = *(const float4*)(Wall + (f4 * 4 + 0) * 128 + c0);
        float4 wf1 = *(const float4*)(Wall + (f4 * 4 + 1) * 128 + c0);
        float4 wf2 = *(const float4*)(Wall + (f4 * 4 + 2) * 128 + c0);
        float4 wf3 = *(const float4*)(Wall + (f4 * 4 + 3) * 128 + c0);
        for (int r = 0; r < 8; r++) {
            float4 xv = *(const float4*)(xs + (r0 + r) * XS_LD + f4 * 4);
            acc[r][0] += xv.x * wf0.x + xv.y * wf1.x + xv.z * wf2.x + xv.w * wf3.x;
            acc[r][1] += xv.x * wf0.y + xv.y * wf1.y + xv.z * wf2.y + xv.w * wf3.y;
            acc[r][2] += xv.x * wf0.z + xv.y * wf1.z + xv.z * wf2.z + xv.w * wf3.z;
            acc[r][3] += xv.x * wf0.w + xv.y * wf1.w + xv.z * wf2.w + xv.w * wf3.w;
        }
    }

    float4 cb = *(const float4*)(cbias + c0);
    for (int r = 0; r < 8; r++) {
        int row = row0 + r0 + r;
        if (row < N_NODES) {
            ushort4 o;
            o.x = f2bf(acc[r][0] + cb.x);
            o.y = f2bf(acc[r][1] + cb.y);
            o.z = f2bf(acc[r][2] + cb.z);
            o.w = f2bf(acc[r][3] + cb.w);
            *(ushort4*)(c + (size_t)row * 128 + c0) = o;
        }
    }

    int j = t & 7;
    const float* arow = aT + j * XS_LD;
    for (int pass = 0; pass < 2; pass++) {
        int r = (t >> 3) + pass * 32;
        const float* xrow = xs + r * XS_LD;
        float accp = 0.f;
        for (int f4 = 0; f4 < 32; f4++) {
            float4 xv = *(const float4*)(xrow + f4 * 4);
            float4 av = *(const float4*)(arow + f4 * 4);
            accp += xv.x * av.x + xv.y * av.y + xv.z * av.z + xv.w * av.w;
        }
        int row = row0 + r;
        if (row < N_NODES) p[(size_t)row * 8 + j] = accp;
    }
}

// ---- per-(bucket,tile) histogram, bucket-major layout hist[b*T + tile] ----
__global__ __launch_bounds__(256) void k_hist(const int* __restrict__ erow,
                                              int* __restrict__ hist) {
    __shared__ int lh[NB];
    int t = threadIdx.x;
    int tile = blockIdx.x;
    for (int i = t; i < NB; i += 256) lh[i] = 0;
    __syncthreads();
    int base = tile * TILE_E;
    #pragma unroll
    for (int i = 0; i < TILE_E / 256; i++) {
        int e = base + i * 256 + t;
        if (e < N_EDGES) atomicAdd(&lh[erow[e] >> BSH], 1);
    }
    __syncthreads();
    for (int i = t; i < NB; i += 256) hist[i * T_TILES + tile] = lh[i];
}

// ---- generalized exclusive scan (3 passes, in-place on data) ----
__global__ __launch_bounds__(256) void k_scan1g(int* __restrict__ data,
                                                int* __restrict__ bsums, int n) {
    __shared__ int sd[256];
    int t = threadIdx.x;
    int b = blockIdx.x;
    int i0 = b * 1024 + t * 4;
    int v0 = (i0 + 0 < n) ? data[i0 + 0] : 0;
    int v1 = (i0 + 1 < n) ? data[i0 + 1] : 0;
    int v2 = (i0 + 2 < n) ? data[i0 + 2] : 0;
    int v3 = (i0 + 3 < n) ? data[i0 + 3] : 0;
    int ts = v0 + v1 + v2 + v3;
    sd[t] = ts;
    __syncthreads();
    for (int s = 1; s < 256; s <<= 1) {
        int add = (t >= s) ? sd[t - s] : 0;
        __syncthreads();
        sd[t] += add;
        __syncthreads();
    }
    int base = sd[t] - ts;
    if (i0 + 0 < n) data[i0 + 0] = base;
    if (i0 + 1 < n) data[i0 + 1] = base + v0;
    if (i0 + 2 < n) data[i0 + 2] = base + v0 + v1;
    if (i0 + 3 < n) data[i0 + 3] = base + v0 + v1 + v2;
    if (t == 255) bsums[b] = sd[255];
}

__global__ void k_scan2g(int* __restrict__ bsums, int B) {
    __shared__ int sd[256];
    int t = threadIdx.x;
    int v = (t < B) ? bsums[t] : 0;
    sd[t] = v;
    __syncthreads();
    for (int s = 1; s < 256; s <<= 1) {
        int add = (t >= s) ? sd[t - s] : 0;
        __syncthreads();
        sd[t] += add;
        __syncthreads();
    }
    if (t < B) bsums[t] = sd[t] - v;
}

__global__ void k_scan3g(int* __restrict__ data, const int* __restrict__ bsums, int n) {
    int i = blockIdx.x * 256 + threadIdx.x;
    if (i < n) data[i] += bsums[i >> 10];
}

// ---- bucket scatter: LDS-reorder each tile by bucket, coalesced copy-out ----
__global__ __launch_bounds__(256) void k_bucket_scatter(const int* __restrict__ erow,
                                                        const int* __restrict__ ecol,
                                                        const int* __restrict__ hist,
                                                        uint2* __restrict__ bucketed) {
    __shared__ int lh[NB];      // hist -> exclusive local start (const after scan)
    __shared__ int lcur[NB];    // cursor, later reused as gbase
    __shared__ uint2 buf[TILE_E];
    int t = threadIdx.x;
    int tile = blockIdx.x;
    int base = tile * TILE_E;
    int cnt = N_EDGES - base; if (cnt > TILE_E) cnt = TILE_E;

    for (int i = t; i < NB; i += 256) lh[i] = 0;
    __syncthreads();

    int rows[TILE_E / 256], cols[TILE_E / 256];
    #pragma unroll
    for (int i = 0; i < TILE_E / 256; i++) {
        int e = base + i * 256 + t;
        if (e < N_EDGES) {
            rows[i] = erow[e];
            cols[i] = ecol[e];
            atomicAdd(&lh[rows[i] >> BSH], 1);
        } else rows[i] = -1;
    }
    __syncthreads();

    // exclusive scan of lh (NB entries) by wave 0; write to both lh and lcur
    if (t < 64) {
        int carry = 0;
        for (int cch = 0; cch < (NB + 63) / 64; cch++) {
            int i = cch * 64 + t;
            int v = (i < NB) ? lh[i] : 0;
            int s = v;
            #pragma unroll
            for (int d = 1; d < 64; d <<= 1) {
                int u = __shfl_up(s, d);
                if (t >= d) s += u;
            }
            int excl = s - v + carry;
            if (i < NB) { lh[i] = excl; lcur[i] = excl; }
            carry += __shfl(s, 63);
        }
    }
    __syncthreads();

    // scatter into LDS (bucket-sorted within tile)
    #pragma unroll
    for (int i = 0; i < TILE_E / 256; i++) {
        if (rows[i] >= 0) {
            int b = rows[i] >> BSH;
            int pos = atomicAdd(&lcur[b], 1);
            buf[pos] = make_uint2((unsigned)rows[i], (unsigned)cols[i]);
        }
    }
    __syncthreads();

    // reload lcur as global base for this (bucket, tile)
    for (int i = t; i < NB; i += 256) lcur[i] = hist[i * T_TILES + tile];
    __syncthreads();

    for (int jj = t; jj < cnt; jj += 256) {
        uint2 pr = buf[jj];
        int b = (int)pr.x >> BSH;
        int gpos = lcur[b] + (jj - lh[b]);
        bucketed[gpos] = pr;
    }
}

// ---- per-bucket: row-offsets (CSR) + softmax + fine scatter (L2-local) ----
__global__ __launch_bounds__(256) void k_edge_compute(const uint2* __restrict__ bucketed,
                                                      const int* __restrict__ hist,
                                                      const float* __restrict__ p,
                                                      const float* __restrict__ aW2,
                                                      const float* __restrict__ ab1,
                                                      const float* __restrict__ ab2,
                                                      int* __restrict__ offs,
                                                      int* __restrict__ csr_col,
                                                      unsigned int* __restrict__ csr_w) {
    __shared__ int rcur[256];
    __shared__ int wtot[4];
    int b = blockIdx.x;
    int t = threadIdx.x;
    int bstart = hist[b * T_TILES];
    int bend = (b + 1 < NB) ? hist[(b + 1) * T_TILES] : N_EDGES;
    int row0 = b << BSH;
    int nrows = N_NODES - row0; if (nrows > 256) nrows = 256;

    rcur[t] = 0;
    __syncthreads();
    // pass 1: row histogram
    for (int i = bstart + t; i < bend; i += 256)
        atomicAdd(&rcur[(int)bucketed[i].x - row0], 1);
    __syncthreads();
    // exclusive scan of 256 via wave scan + wave totals
    int v = rcur[t];
    int s = v;
    #pragma unroll
    for (int d = 1; d < 64; d <<= 1) {
        int u = __shfl_up(s, d);
        if ((t & 63) >= d) s += u;
    }
    if ((t & 63) == 63) wtot[t >> 6] = s;
    __syncthreads();
    int add = 0;
    for (int w = 0; w < (t >> 6); w++) add += wtot[w];
    int pos0 = bstart + (s - v + add);
    __syncthreads();
    rcur[t] = pos0;
    if (t < nrows) offs[row0 + t] = pos0;
    if (b == NB - 1 && t == 0) offs[N_NODES] = N_EDGES;
    __syncthreads();

    // pass 2: softmax + scatter within bucket region
    for (int i = bstart + t; i < bend; i += 256) {
        uint2 pr = bucketed[i];
        int r = (int)pr.x;
        int cl = (int)pr.y;
        float4 pc = *(const float4*)(p + (size_t)cl * 8);
        float4 prr = *(const float4*)(p + (size_t)r * 8 + 4);
        float h0 = pc.x + prr.x + ab1[0];
        float h1 = pc.y + prr.y + ab1[1];
        float h2 = pc.z + prr.z + ab1[2];
        float h3 = pc.w + prr.w + ab1[3];
        float sc[4];
        #pragma unroll
        for (int jq = 0; jq < 4; jq++)
            sc[jq] = h0 * aW2[jq] + h1 * aW2[4 + jq] + h2 * aW2[8 + jq] + h3 * aW2[12 + jq] + ab2[jq];
        float m = fmaxf(fmaxf(sc[0], sc[1]), fmaxf(sc[2], sc[3]));
        float e0 = expf(sc[0] - m), e1 = expf(sc[1] - m), e2 = expf(sc[2] - m), e3 = expf(sc[3] - m);
        float inv = 1.f / (e0 + e1 + e2 + e3);
        unsigned int w01 = (unsigned int)f2bf(e0 * inv) | ((unsigned int)f2bf(e1 * inv) << 16);
        unsigned int w23 = (unsigned int)f2bf(e2 * inv) | ((unsigned int)f2bf(e3 * inv) << 16);
        int pos = atomicAdd(&rcur[r - row0], 1);
        csr_col[pos] = cl;
        uint2 wp; wp.x = w01; wp.y = w23;
        *(uint2*)(csr_w + (size_t)pos * 2) = wp;
    }
}

// ---- aggregation (pull): wave per node; bf16 c + bf16 w; norm + classifier fused ----
static __device__ __forceinline__ float bf_lo(unsigned int u) { return __uint_as_float(u << 16); }
static __device__ __forceinline__ float bf_hi(unsigned int u) { return __uint_as_float(u & 0xffff0000u); }

__global__ __launch_bounds__(256) void k_agg(const int* __restrict__ csr_col,
                                             const unsigned int* __restrict__ csr_w,
                                             const unsigned int* __restrict__ c4,
                                             const int* __restrict__ offsets,
                                             const float* __restrict__ bch,
                                             const float* __restrict__ Wcls,
                                             const float* __restrict__ bcls,
                                             float* __restrict__ out) {
    int wid = (blockIdx.x * 256 + threadIdx.x) >> 6;
    int lane = threadIdx.x & 63;
    if (wid >= N_NODES) return;
    int n = wid;
    int start = offsets[n];
    int end = offsets[n + 1];
    int ch = lane >> 4;
    int pair = ch >> 1;
    int hi = ch & 1;

    float acc0 = 0.f, acc1 = 0.f;
    int idx = start;
    for (; idx + 3 < end; idx += 4) {
        int col0 = csr_col[idx];
        int col1 = csr_col[idx + 1];
        int col2 = csr_col[idx + 2];
        int col3 = csr_col[idx + 3];
        unsigned int wu0 = csr_w[(size_t)(idx + 0) * 2 + pair];
        unsigned int wu1 = csr_w[(size_t)(idx + 1) * 2 + pair];
        unsigned int wu2 = csr_w[(size_t)(idx + 2) * 2 + pair];
        unsigned int wu3 = csr_w[(size_t)(idx + 3) * 2 + pair];
        unsigned int u0 = c4[(size_t)col0 * 64 + lane];
        unsigned int u1 = c4[(size_t)col1 * 64 + lane];
        unsigned int u2 = c4[(size_t)col2 * 64 + lane];
        unsigned int u3 = c4[(size_t)col3 * 64 + lane];
        float w0 = hi ? bf_hi(wu0) : bf_lo(wu0);
        float w1 = hi ? bf_hi(wu1) : bf_lo(wu1);
        float w2 = hi ? bf_hi(wu2) : bf_lo(wu2);
        float w3 = hi ? bf_hi(wu3) : bf_lo(wu3);
        acc0 += w0 * bf_lo(u0) + w1 * bf_lo(u1) + w2 * bf_lo(u2) + w3 * bf_lo(u3);
        acc1 += w0 * bf_hi(u0) + w1 * bf_hi(u1) + w2 * bf_hi(u2) + w3 * bf_hi(u3);
    }
    for (; idx < end; idx++) {
        int col0 = csr_col[idx];
        unsigned int wu0 = csr_w[(size_t)idx * 2 + pair];
        unsigned int u0 = c4[(size_t)col0 * 64 + lane];
        float w0 = hi ? bf_hi(wu0) : bf_lo(wu0);
        acc0 += w0 * bf_lo(u0);
        acc1 += w0 * bf_hi(u0);
    }

    int f0 = 2 * lane, f1 = 2 * lane + 1;
    float v0 = acc0 + bch[f0];
    float v1 = acc1 + bch[f1];

    float ss = v0 * v0 + v1 * v1;
    #pragma unroll
    for (int m = 1; m <= 8; m <<= 1) ss += __shfl_xor(ss, m);
    float inv = 1.f / fmaxf(sqrtf(ss), 1e-12f);
    v0 *= inv;
    v1 *= inv;

    *(float2*)(out + (size_t)n * 128 + f0) = make_float2(v0, v1);

    float pl = v0 * Wcls[f0] + v1 * Wcls[f1];
    #pragma unroll
    for (int m = 1; m <= 32; m <<= 1) pl += __shfl_xor(pl, m);
    if (lane == 0) out[(size_t)N_NODES * 128 + n] = pl + bcls[0];
}

extern "C" void kernel_launch(void* const* d_in, const int* in_sizes, int n_in,
                              void* d_out, int out_size, void* d_ws, size_t ws_size,
                              hipStream_t stream) {
    const float* x    = (const float*)d_in[0];
    const int*   erow = (const int*)d_in[1];
    const int*   ecol = (const int*)d_in[2];
    const float* aW1  = (const float*)d_in[3];
    const float* ab1  = (const float*)d_in[4];
    const float* aW2  = (const float*)d_in[5];
    const float* ab2  = (const float*)d_in[6];
    const float* Wlin = (const float*)d_in[7];
    const float* blin = (const float*)d_in[8];
    const float* Wconv= (const float*)d_in[9];
    const float* bch  = (const float*)d_in[10];
    const float* Wcls = (const float*)d_in[11];
    const float* bcls = (const float*)d_in[12];
    float* out = (float*)d_out;

    char* ws = (char*)d_ws;
    float*          Wall    = (float*)(ws + WS_WALL);
    float*          cbias   = (float*)(ws + WS_CBIAS);
    float*          p       = (float*)(ws + WS_P);
    unsigned short* c       = (unsigned short*)(ws + WS_C);
    int*            offs    = (int*)(ws + WS_OFFS);
    int*            hist    = (int*)(ws + WS_HIST);
    int*            hsums   = (int*)(ws + WS_HSUMS);
    uint2*          bucketed= (uint2*)(ws + WS_BUCK);
    int*            csr_col = (int*)(ws + WS_CSRCOL);
    unsigned int*   csr_w   = (unsigned int*)(ws + WS_CSRW);

    int scan_blocks = (NHIST + 1023) / 1024;   // 150

    k_fuse<<<65, 256, 0, stream>>>(Wlin, Wconv, blin, Wall, cbias);
    k_hist<<<T_TILES, 256, 0, stream>>>(erow, hist);
    k_cgemm<<<(N_NODES + 63) / 64, 256, 0, stream>>>(x, Wall, cbias, aW1, c, p);
    k_scan1g<<<scan_blocks, 256, 0, stream>>>(hist, hsums, NHIST);
    k_scan2g<<<1, 256, 0, stream>>>(hsums, scan_blocks);
    k_scan3g<<<(NHIST + 255) / 256, 256, 0, stream>>>(hist, hsums, NHIST);
    k_bucket_scatter<<<T_TILES, 256, 0, stream>>>(erow, ecol, hist, bucketed);
    k_edge_compute<<<NB, 256, 0, stream>>>(bucketed, hist, p, aW2, ab1, ab2,
                                           offs, csr_col, csr_w);
    k_agg<<<(N_NODES + 3) / 4, 256, 0, stream>>>(csr_col, csr_w, (const unsigned int*)c,
                                                 offs, bch, Wcls, bcls, out);
}